// Round 12
// baseline (453.764 us; speedup 1.0000x reference)
//
#include <hip/hip_runtime.h>
#include <math.h>

// Problem constants (fixed by setup_inputs)
#define B_    8
#define T_    8192
#define LIN   1536
#define D_    768
#define H_    8
#define E_    96
#define TT    16            // tokens per block in kB (24KB LDS -> 6 blocks/CU)
#define NWA   8192          // total waves in kA (2048 blocks x 4 waves); 8 tokens/wave
#define NCH3  64            // chunks per batch in k3
#define CHT3  (T_ / NCH3)   // 128 tokens per chunk (32 per wave)

// MEASUREMENT ROUND: pipeline is byte-identical to R11 (passed, 245 us) except
// kA is launched 3x (idempotent: writes xnb deterministically from unmodified
// input x). total ~= 245 + 2*(kA + gap)  =>  kA = (total - 245)/2 - gap.

typedef float f32x4 __attribute__((ext_vector_type(4)));
typedef short s16x8 __attribute__((ext_vector_type(8)));
typedef short s16x4 __attribute__((ext_vector_type(4)));

static __device__ __forceinline__ float fast_sigmoid(float v) {
    return 1.0f / (1.0f + __expf(-v));
}
static __device__ __forceinline__ float fast_tanh(float v) {
    float t = __expf(-2.0f * v);
    return (1.0f - t) / (1.0f + t);
}
static __device__ __forceinline__ short f2bf(float f) {   // RNE f32 -> bf16 bits
    unsigned u = __float_as_uint(f);
    unsigned r = (u + 0x7FFFu + ((u >> 16) & 1u)) >> 16;
    return (short)r;
}
static __device__ __forceinline__ float bf2f(short s) {
    return __uint_as_float(((unsigned)(unsigned short)s) << 16);
}

// ---------------------------------------------------------------------------
// Kernel 0: weight prep. Wa,Wb [h][e][f] f32 -> wtA,wtB [h][f][e] bf16.
// ---------------------------------------------------------------------------
__global__ __launch_bounds__(256)
void k0_wprep(const float* __restrict__ Wa, const float* __restrict__ Wb,
              short* __restrict__ wtA, short* __restrict__ wtB)
{
    int o = blockIdx.x * 256 + threadIdx.x;
    if (o >= H_ * E_ * E_) return;
    int e = o % E_;
    int f = (o / E_) % E_;
    int h = o / (E_ * E_);
    int in = h * E_ * E_ + e * E_ + f;
    wtA[o] = f2bf(Wa[in]);
    wtB[o] = f2bf(Wb[in]);
}

// ---------------------------------------------------------------------------
// Kernel A: resize + LayerNorm; wave owns 8 contiguous tokens; 1-ahead
// prefetch. Byte-identical to R11 (passed).
// ---------------------------------------------------------------------------
__global__ __launch_bounds__(256)
void kA_resln(const float* __restrict__ x,
              const float* __restrict__ gamma, const float* __restrict__ beta,
              short* __restrict__ xnb)
{
    const int tid  = threadIdx.x;
    const int lane = tid & 63;
    const int wv   = tid >> 6;
    const int gw   = blockIdx.x * 4 + wv;   // 0..NWA-1

    const float SCALE = (float)(1535.0 / 767.0);
    float gm[12], btv[12], wl[12];
    #pragma unroll
    for (int c = 0; c < 3; ++c)
        #pragma unroll
        for (int d = 0; d < 4; ++d) {
            int k = 4 * c + d;
            int j = 256 * c + 4 * lane + d;
            float pos = (float)j * SCALE;
            int a = (int)floorf(pos);
            if (a > LIN - 1) a = LIN - 1;
            wl[k] = pos - (float)a;
            gm[k]  = gamma[j];
            btv[k] = beta[j];
        }
    const bool last = (lane == 63);

    const size_t tok0 = (size_t)gw * 8;
    const float* base = x + tok0 * LIN;

    f32x4 La0 = *(const f32x4*)&base[           8 * lane];
    f32x4 Lb0 = *(const f32x4*)&base[           8 * lane + 4];
    f32x4 La1 = *(const f32x4*)&base[512  +     8 * lane];
    f32x4 Lb1 = *(const f32x4*)&base[512  +     8 * lane + 4];
    f32x4 La2 = *(const f32x4*)&base[1024 +     8 * lane];
    f32x4 Lb2 = *(const f32x4*)&base[1024 +     8 * lane + 4];

    #pragma unroll
    for (int tt = 0; tt < 8; ++tt) {
        f32x4 Na0, Nb0, Na1, Nb1, Na2, Nb2;
        if (tt < 7) {
            const float* nr = base + (size_t)(tt + 1) * LIN;
            Na0 = *(const f32x4*)&nr[           8 * lane];
            Nb0 = *(const f32x4*)&nr[           8 * lane + 4];
            Na1 = *(const f32x4*)&nr[512  +     8 * lane];
            Nb1 = *(const f32x4*)&nr[512  +     8 * lane + 4];
            Na2 = *(const f32x4*)&nr[1024 +     8 * lane];
            Nb2 = *(const f32x4*)&nr[1024 +     8 * lane + 4];
        }

        float xr[12];
        float sum = 0.0f, ssq = 0.0f;
        #pragma unroll
        for (int c = 0; c < 3; ++c) {
            f32x4 A = (c == 0) ? La0 : (c == 1) ? La1 : La2;
            f32x4 Bv = (c == 0) ? Lb0 : (c == 1) ? Lb1 : Lb2;
            #pragma unroll
            for (int d = 0; d < 4; ++d) {
                int k = 4 * c + d;
                int idx = (d & 1) * 2;
                float lo = (d < 2) ? A[idx]     : Bv[idx];
                float hi = (d < 2) ? A[idx + 1] : Bv[idx + 1];
                if (c == 2 && d == 3 && last && wl[k] == 0.0f)
                    lo = Lb2[3];               // j=767 clamp
                float v = lo * (1.0f - wl[k]) + hi * wl[k];
                xr[k] = v; sum += v; ssq = fmaf(v, v, ssq);
            }
        }

        #pragma unroll
        for (int o = 1; o < 64; o <<= 1) {
            sum += __shfl_xor(sum, o, 64);
            ssq += __shfl_xor(ssq, o, 64);
        }
        float mu = sum * (1.0f / D_);
        float rs = 1.0f / sqrtf(ssq * (1.0f / D_) - mu * mu + 1e-5f);

        short* dst = xnb + (tok0 + tt) * D_;
        #pragma unroll
        for (int c = 0; c < 3; ++c) {
            s16x4 p;
            #pragma unroll
            for (int d = 0; d < 4; ++d) {
                int k = 4 * c + d;
                p[d] = f2bf((xr[k] - mu) * rs * gm[k] + btv[k]);
            }
            *(s16x4*)&dst[256 * c + 4 * lane] = p;
        }

        if (tt < 7) {
            La0 = Na0; Lb0 = Nb0; La1 = Na1; Lb1 = Nb1; La2 = Na2; Lb2 = Nb2;
        }
    }
}

// ---------------------------------------------------------------------------
// Kernel B: MFMA scoring, 16-token tile. Byte-identical to R11 (passed).
// ---------------------------------------------------------------------------
__global__ __launch_bounds__(256)
void kB_score(const short* __restrict__ xnb,
              const short* __restrict__ wtA, const short* __restrict__ wtB,
              const float* __restrict__ ba, const float* __restrict__ bb,
              const float* __restrict__ Wc, const float* __restrict__ bc,
              float* __restrict__ s_out)
{
    __shared__ __align__(16) short xnt[TT * D_];   // 24 KB bf16 tile
    __shared__ float red2[TT][4];

    const int tid  = threadIdx.x;
    const int lane = tid & 63;
    const int wv   = tid >> 6;
    const int bt0  = blockIdx.x * TT;

    #pragma unroll
    for (int i = 0; i < 6; ++i) {
        int chunk = i * 256 + tid;
        int tok   = chunk / 96;
        int e     = chunk % 96;
        s16x8 v = *(const s16x8*)&xnb[(size_t)(bt0 + tok) * D_ + e * 8];
        int base = tok * D_;
        int swz  = (tok & 7) << 3;
        #pragma unroll
        for (int h = 0; h < 8; ++h) {
            int sidx = (base + h * E_ + e) ^ swz;
            xnt[sidx] = v[h];
        }
    }
    __syncthreads();

    const int ln15 = lane & 15;
    const int q    = lane >> 4;
    const int tokA = ln15;
    const int swzA = (tokA & 7) << 3;

    float hacc[4] = {0.0f, 0.0f, 0.0f, 0.0f};

    #pragma unroll
    for (int hh = 0; hh < 2; ++hh) {
        const int h = wv * 2 + hh;
        s16x8 afr[3];
        #pragma unroll
        for (int kk = 0; kk < 3; ++kk) {
            int sidx = (tokA * D_ + h * E_ + kk * 32 + q * 8) ^ swzA;
            afr[kk] = *(const s16x8*)&xnt[sidx];
        }
        f32x4 accA[6], accG[6];
        #pragma unroll
        for (int nt = 0; nt < 6; ++nt) {
            accA[nt] = (f32x4){0.f, 0.f, 0.f, 0.f};
            accG[nt] = (f32x4){0.f, 0.f, 0.f, 0.f};
        }
        #pragma unroll
        for (int nt = 0; nt < 6; ++nt) {
            const short* rowA = wtA + h * (E_ * E_) + (nt * 16 + ln15) * E_ + q * 8;
            const short* rowB = wtB + h * (E_ * E_) + (nt * 16 + ln15) * E_ + q * 8;
            #pragma unroll
            for (int kk = 0; kk < 3; ++kk) {
                s16x8 bA = *(const s16x8*)(rowA + kk * 32);
                s16x8 bG = *(const s16x8*)(rowB + kk * 32);
                accA[nt] = __builtin_amdgcn_mfma_f32_16x16x32_bf16(afr[kk], bA, accA[nt], 0, 0, 0);
                accG[nt] = __builtin_amdgcn_mfma_f32_16x16x32_bf16(afr[kk], bG, accG[nt], 0, 0, 0);
            }
        }
        float v0 = 0.f, v1 = 0.f, v2 = 0.f, v3 = 0.f;
        #pragma unroll
        for (int nt = 0; nt < 6; ++nt) {
            int f = nt * 16 + ln15;
            float bav = ba[h * E_ + f];
            float bbv = bb[h * E_ + f];
            float wcv = Wc[h * E_ + f];
            v0 += fast_tanh(accA[nt][0] + bav) * fast_sigmoid(accG[nt][0] + bbv) * wcv;
            v1 += fast_tanh(accA[nt][1] + bav) * fast_sigmoid(accG[nt][1] + bbv) * wcv;
            v2 += fast_tanh(accA[nt][2] + bav) * fast_sigmoid(accG[nt][2] + bbv) * wcv;
            v3 += fast_tanh(accA[nt][3] + bav) * fast_sigmoid(accG[nt][3] + bbv) * wcv;
        }
        hacc[0] += v0; hacc[1] += v1; hacc[2] += v2; hacc[3] += v3;
    }

    #pragma unroll
    for (int r = 0; r < 4; ++r) {
        float v = hacc[r];
        v += __shfl_xor(v, 1, 64);
        v += __shfl_xor(v, 2, 64);
        v += __shfl_xor(v, 4, 64);
        v += __shfl_xor(v, 8, 64);
        hacc[r] = v;
    }
    if (ln15 == 0) {
        #pragma unroll
        for (int r = 0; r < 4; ++r)
            red2[q * 4 + r][wv] = hacc[r];
    }
    __syncthreads();

    if (tid < TT) {
        float bcsum = 0.0f;
        #pragma unroll
        for (int h2 = 0; h2 < H_; ++h2) bcsum += bc[h2];
        s_out[bt0 + tid] = (red2[tid][0] + red2[tid][1] + red2[tid][2] + red2[tid][3]
                            + bcsum) * (1.0f / H_);
    }
}

// ---------------------------------------------------------------------------
// Kernel 2a: per-1024-token chunk max + sum(exp(s - m_c)). grid = B*8.
// ---------------------------------------------------------------------------
__global__ __launch_bounds__(256)
void k2a_chunk(const float* __restrict__ s, float* __restrict__ mzc)
{
    __shared__ float red[8];
    const int blk = blockIdx.x, tid = threadIdx.x, lane = tid & 63, wv = tid >> 6;
    const float* sb = s + (size_t)blk * 1024;

    float v0 = sb[tid], v1 = sb[tid + 256], v2 = sb[tid + 512], v3 = sb[tid + 768];

    float m = fmaxf(fmaxf(v0, v1), fmaxf(v2, v3));
    #pragma unroll
    for (int o = 32; o > 0; o >>= 1) m = fmaxf(m, __shfl_down(m, o, 64));
    if (lane == 0) red[wv] = m;
    __syncthreads();
    m = fmaxf(fmaxf(red[0], red[1]), fmaxf(red[2], red[3]));
    __syncthreads();

    float z = __expf(v0 - m) + __expf(v1 - m) + __expf(v2 - m) + __expf(v3 - m);
    #pragma unroll
    for (int o = 32; o > 0; o >>= 1) z += __shfl_down(z, o, 64);
    if (lane == 0) red[wv] = z;
    __syncthreads();
    if (tid == 0) {
        mzc[blk * 2]     = m;
        mzc[blk * 2 + 1] = red[0] + red[1] + red[2] + red[3];
    }
}

// ---------------------------------------------------------------------------
// Kernel 2b: combine 8 chunk (m,z) -> per-batch (m, 1/z). grid = B, 1 wave.
// ---------------------------------------------------------------------------
__global__ __launch_bounds__(64)
void k2b_comb(const float* __restrict__ mzc, float* __restrict__ mz)
{
    const int b = blockIdx.x, lane = threadIdx.x;
    float mloc = (lane < 8) ? mzc[(b * 8 + lane) * 2]     : -INFINITY;
    float zloc = (lane < 8) ? mzc[(b * 8 + lane) * 2 + 1] : 0.0f;
    float m = mloc;
    m = fmaxf(m, __shfl_xor(m, 1, 64));
    m = fmaxf(m, __shfl_xor(m, 2, 64));
    m = fmaxf(m, __shfl_xor(m, 4, 64));
    float z = zloc * __expf(mloc - m);
    z += __shfl_xor(z, 1, 64);
    z += __shfl_xor(z, 2, 64);
    z += __shfl_xor(z, 4, 64);
    if (lane == 0) { mz[b * 2] = m; mz[b * 2 + 1] = 1.0f / z; }
}

// ---------------------------------------------------------------------------
// Kernel 3: pooling from bf16 xn; block-reduced partials (64/batch).
// ---------------------------------------------------------------------------
__global__ __launch_bounds__(256)
void k3_pool(const short* __restrict__ xnb, const float* __restrict__ s,
             const float* __restrict__ mz, float* __restrict__ partial)
{
    __shared__ float red[4][D_];   // 12 KB
    const int tid  = threadIdx.x;
    const int lane = tid & 63;
    const int wv   = tid >> 6;
    const int b    = blockIdx.x / NCH3, ch = blockIdx.x % NCH3;
    const int t0   = b * T_ + ch * CHT3 + wv * 32;

    const float m   = mz[b * 2];
    const float inv = mz[b * 2 + 1];

    float acc[12];
    #pragma unroll
    for (int k = 0; k < 12; ++k) acc[k] = 0.0f;

    for (int tt = 0; tt < 32; ++tt) {
        int t = t0 + tt;
        const short* row = xnb + (size_t)t * D_;
        float wt = __expf(s[t] - m) * inv;
        s16x8 v0 = *(const s16x8*)&row[8 * lane];
        s16x4 v1 = *(const s16x4*)&row[512 + 4 * lane];
        #pragma unroll
        for (int k = 0; k < 8; ++k) acc[k] = fmaf(wt, bf2f(v0[k]), acc[k]);
        #pragma unroll
        for (int k = 0; k < 4; ++k) acc[8 + k] = fmaf(wt, bf2f(v1[k]), acc[8 + k]);
    }

    *(f32x4*)&red[wv][8 * lane]       = (f32x4){acc[0], acc[1], acc[2], acc[3]};
    *(f32x4*)&red[wv][8 * lane + 4]   = (f32x4){acc[4], acc[5], acc[6], acc[7]};
    *(f32x4*)&red[wv][512 + 4 * lane] = (f32x4){acc[8], acc[9], acc[10], acc[11]};
    __syncthreads();

    float* p = partial + (size_t)blockIdx.x * D_;
    #pragma unroll
    for (int k = 0; k < 3; ++k) {
        int j = tid + k * 256;
        p[j] = ((red[0][j] + red[1][j]) + red[2][j]) + red[3][j];
    }
}

// ---------------------------------------------------------------------------
// Kernel 4: reduce 64 chunk-partials per batch -> out[b, 768].
// ---------------------------------------------------------------------------
__global__ __launch_bounds__(256)
void k4_reduce(const float* __restrict__ partial, float* __restrict__ out)
{
    const int b = blockIdx.x, tid = threadIdx.x;
    #pragma unroll
    for (int k = 0; k < 3; ++k) {
        int j = tid + k * 256;
        const float* p = partial + (size_t)b * NCH3 * D_ + j;
        float sum = 0.0f;
        for (int c = 0; c < NCH3; ++c) sum += p[(size_t)c * D_];
        out[b * D_ + j] = sum;
    }
}

// ---------------------------------------------------------------------------
extern "C" void kernel_launch(void* const* d_in, const int* in_sizes, int n_in,
                              void* d_out, int out_size, void* d_ws, size_t ws_size,
                              hipStream_t stream)
{
    const float* x     = (const float*)d_in[0];
    // d_in[1] = lens (unused: uniform == L_IN, reference ignores it)
    const float* gamma = (const float*)d_in[2];
    const float* beta  = (const float*)d_in[3];
    const float* Wa    = (const float*)d_in[4];
    const float* ba    = (const float*)d_in[5];
    const float* Wb    = (const float*)d_in[6];
    const float* bb    = (const float*)d_in[7];
    const float* Wc    = (const float*)d_in[8];
    const float* bc    = (const float*)d_in[9];
    float* out = (float*)d_out;

    float* ws      = (float*)d_ws;
    float* s       = ws;                                   // B*T f32
    float* mzc     = s + B_ * T_;                          // 128 f32
    float* mz      = mzc + 128;                            // 16 f32
    float* partial = mz + 16;                              // B*64*768 f32
    short* wtA     = (short*)(partial + (size_t)B_ * NCH3 * D_);
    short* wtB     = wtA + H_ * E_ * E_;
    short* xnb     = wtB + H_ * E_ * E_;                   // B*T*768 bf16 (96 MB)

    hipLaunchKernelGGL(k0_wprep, dim3((H_ * E_ * E_ + 255) / 256), dim3(256), 0, stream,
                       Wa, Wb, wtA, wtB);
    // kA launched 3x (idempotent) — MEASUREMENT: kA = (total - 245us)/2 - gap
    hipLaunchKernelGGL(kA_resln, dim3(NWA / 4), dim3(256), 0, stream,
                       x, gamma, beta, xnb);
    hipLaunchKernelGGL(kA_resln, dim3(NWA / 4), dim3(256), 0, stream,
                       x, gamma, beta, xnb);
    hipLaunchKernelGGL(kA_resln, dim3(NWA / 4), dim3(256), 0, stream,
                       x, gamma, beta, xnb);
    hipLaunchKernelGGL(kB_score, dim3(B_ * T_ / TT), dim3(256), 0, stream,
                       xnb, wtA, wtB, ba, bb, Wc, bc, s);
    hipLaunchKernelGGL(k2a_chunk, dim3(B_ * 8), dim3(256), 0, stream, s, mzc);
    hipLaunchKernelGGL(k2b_comb, dim3(B_), dim3(64), 0, stream, mzc, mz);
    hipLaunchKernelGGL(k3_pool, dim3(B_ * NCH3), dim3(256), 0, stream,
                       xnb, s, mz, partial);
    hipLaunchKernelGGL(k4_reduce, dim3(B_), dim3(256), 0, stream, partial, out);
}

// Round 13
// 236.809 us; speedup vs baseline: 1.9162x; 1.9162x over previous
//
#include <hip/hip_runtime.h>
#include <math.h>

// Problem constants (fixed by setup_inputs)
#define B_    8
#define T_    8192
#define LIN   1536
#define D_    768
#define H_    8
#define E_    96
#define TT    16            // tokens per block in kB (24KB LDS -> 6 blocks/CU)
#define NWA   8192          // total waves in kA (2048 blocks x 4 waves); 8 tokens/wave
#define NCH3  64            // chunks per batch in k3
#define CHT3  (T_ / NCH3)   // 128 tokens per chunk (32 per wave)

typedef float f32x4 __attribute__((ext_vector_type(4)));
typedef short s16x8 __attribute__((ext_vector_type(8)));
typedef short s16x4 __attribute__((ext_vector_type(4)));

static __device__ __forceinline__ float fast_sigmoid(float v) {
    return 1.0f / (1.0f + __expf(-v));
}
static __device__ __forceinline__ float fast_tanh(float v) {
    float t = __expf(-2.0f * v);
    return (1.0f - t) / (1.0f + t);
}
static __device__ __forceinline__ short f2bf(float f) {   // RNE f32 -> bf16 bits
    unsigned u = __float_as_uint(f);
    unsigned r = (u + 0x7FFFu + ((u >> 16) & 1u)) >> 16;
    return (short)r;
}
static __device__ __forceinline__ float bf2f(short s) {
    return __uint_as_float(((unsigned)(unsigned short)s) << 16);
}

// ---------------------------------------------------------------------------
// Kernel 0: weight prep. Wa,Wb [h][e][f] f32 -> wtA,wtB [h][f][e] bf16.
// ---------------------------------------------------------------------------
__global__ __launch_bounds__(256)
void k0_wprep(const float* __restrict__ Wa, const float* __restrict__ Wb,
              short* __restrict__ wtA, short* __restrict__ wtB)
{
    int o = blockIdx.x * 256 + threadIdx.x;
    if (o >= H_ * E_ * E_) return;
    int e = o % E_;
    int f = (o / E_) % E_;
    int h = o / (E_ * E_);
    int in = h * E_ * E_ + e * E_ + f;
    wtA[o] = f2bf(Wa[in]);
    wtB[o] = f2bf(Wb[in]);
}

// ---------------------------------------------------------------------------
// Kernel A: resize + LayerNorm; wave owns 8 contiguous tokens; 1-ahead
// prefetch. Byte-identical to R11 (passed; measured ~103 us in R12).
// ---------------------------------------------------------------------------
__global__ __launch_bounds__(256)
void kA_resln(const float* __restrict__ x,
              const float* __restrict__ gamma, const float* __restrict__ beta,
              short* __restrict__ xnb)
{
    const int tid  = threadIdx.x;
    const int lane = tid & 63;
    const int wv   = tid >> 6;
    const int gw   = blockIdx.x * 4 + wv;   // 0..NWA-1

    const float SCALE = (float)(1535.0 / 767.0);
    float gm[12], btv[12], wl[12];
    #pragma unroll
    for (int c = 0; c < 3; ++c)
        #pragma unroll
        for (int d = 0; d < 4; ++d) {
            int k = 4 * c + d;
            int j = 256 * c + 4 * lane + d;
            float pos = (float)j * SCALE;
            int a = (int)floorf(pos);
            if (a > LIN - 1) a = LIN - 1;
            wl[k] = pos - (float)a;
            gm[k]  = gamma[j];
            btv[k] = beta[j];
        }
    const bool last = (lane == 63);

    const size_t tok0 = (size_t)gw * 8;
    const float* base = x + tok0 * LIN;

    f32x4 La0 = *(const f32x4*)&base[           8 * lane];
    f32x4 Lb0 = *(const f32x4*)&base[           8 * lane + 4];
    f32x4 La1 = *(const f32x4*)&base[512  +     8 * lane];
    f32x4 Lb1 = *(const f32x4*)&base[512  +     8 * lane + 4];
    f32x4 La2 = *(const f32x4*)&base[1024 +     8 * lane];
    f32x4 Lb2 = *(const f32x4*)&base[1024 +     8 * lane + 4];

    #pragma unroll
    for (int tt = 0; tt < 8; ++tt) {
        f32x4 Na0, Nb0, Na1, Nb1, Na2, Nb2;
        if (tt < 7) {
            const float* nr = base + (size_t)(tt + 1) * LIN;
            Na0 = *(const f32x4*)&nr[           8 * lane];
            Nb0 = *(const f32x4*)&nr[           8 * lane + 4];
            Na1 = *(const f32x4*)&nr[512  +     8 * lane];
            Nb1 = *(const f32x4*)&nr[512  +     8 * lane + 4];
            Na2 = *(const f32x4*)&nr[1024 +     8 * lane];
            Nb2 = *(const f32x4*)&nr[1024 +     8 * lane + 4];
        }

        float xr[12];
        float sum = 0.0f, ssq = 0.0f;
        #pragma unroll
        for (int c = 0; c < 3; ++c) {
            f32x4 A = (c == 0) ? La0 : (c == 1) ? La1 : La2;
            f32x4 Bv = (c == 0) ? Lb0 : (c == 1) ? Lb1 : Lb2;
            #pragma unroll
            for (int d = 0; d < 4; ++d) {
                int k = 4 * c + d;
                int idx = (d & 1) * 2;
                float lo = (d < 2) ? A[idx]     : Bv[idx];
                float hi = (d < 2) ? A[idx + 1] : Bv[idx + 1];
                if (c == 2 && d == 3 && last && wl[k] == 0.0f)
                    lo = Lb2[3];               // j=767 clamp
                float v = lo * (1.0f - wl[k]) + hi * wl[k];
                xr[k] = v; sum += v; ssq = fmaf(v, v, ssq);
            }
        }

        #pragma unroll
        for (int o = 1; o < 64; o <<= 1) {
            sum += __shfl_xor(sum, o, 64);
            ssq += __shfl_xor(ssq, o, 64);
        }
        float mu = sum * (1.0f / D_);
        float rs = 1.0f / sqrtf(ssq * (1.0f / D_) - mu * mu + 1e-5f);

        short* dst = xnb + (tok0 + tt) * D_;
        #pragma unroll
        for (int c = 0; c < 3; ++c) {
            s16x4 p;
            #pragma unroll
            for (int d = 0; d < 4; ++d) {
                int k = 4 * c + d;
                p[d] = f2bf((xr[k] - mu) * rs * gm[k] + btv[k]);
            }
            *(s16x4*)&dst[256 * c + 4 * lane] = p;
        }

        if (tt < 7) {
            La0 = Na0; Lb0 = Nb0; La1 = Na1; Lb1 = Nb1; La2 = Na2; Lb2 = Nb2;
        }
    }
}

// ---------------------------------------------------------------------------
// Kernel B: MFMA scoring, 16-token tile. Byte-identical to R11 (passed).
// ---------------------------------------------------------------------------
__global__ __launch_bounds__(256)
void kB_score(const short* __restrict__ xnb,
              const short* __restrict__ wtA, const short* __restrict__ wtB,
              const float* __restrict__ ba, const float* __restrict__ bb,
              const float* __restrict__ Wc, const float* __restrict__ bc,
              float* __restrict__ s_out)
{
    __shared__ __align__(16) short xnt[TT * D_];   // 24 KB bf16 tile
    __shared__ float red2[TT][4];

    const int tid  = threadIdx.x;
    const int lane = tid & 63;
    const int wv   = tid >> 6;
    const int bt0  = blockIdx.x * TT;

    #pragma unroll
    for (int i = 0; i < 6; ++i) {
        int chunk = i * 256 + tid;
        int tok   = chunk / 96;
        int e     = chunk % 96;
        s16x8 v = *(const s16x8*)&xnb[(size_t)(bt0 + tok) * D_ + e * 8];
        int base = tok * D_;
        int swz  = (tok & 7) << 3;
        #pragma unroll
        for (int h = 0; h < 8; ++h) {
            int sidx = (base + h * E_ + e) ^ swz;
            xnt[sidx] = v[h];
        }
    }
    __syncthreads();

    const int ln15 = lane & 15;
    const int q    = lane >> 4;
    const int tokA = ln15;
    const int swzA = (tokA & 7) << 3;

    float hacc[4] = {0.0f, 0.0f, 0.0f, 0.0f};

    #pragma unroll
    for (int hh = 0; hh < 2; ++hh) {
        const int h = wv * 2 + hh;
        s16x8 afr[3];
        #pragma unroll
        for (int kk = 0; kk < 3; ++kk) {
            int sidx = (tokA * D_ + h * E_ + kk * 32 + q * 8) ^ swzA;
            afr[kk] = *(const s16x8*)&xnt[sidx];
        }
        f32x4 accA[6], accG[6];
        #pragma unroll
        for (int nt = 0; nt < 6; ++nt) {
            accA[nt] = (f32x4){0.f, 0.f, 0.f, 0.f};
            accG[nt] = (f32x4){0.f, 0.f, 0.f, 0.f};
        }
        #pragma unroll
        for (int nt = 0; nt < 6; ++nt) {
            const short* rowA = wtA + h * (E_ * E_) + (nt * 16 + ln15) * E_ + q * 8;
            const short* rowB = wtB + h * (E_ * E_) + (nt * 16 + ln15) * E_ + q * 8;
            #pragma unroll
            for (int kk = 0; kk < 3; ++kk) {
                s16x8 bA = *(const s16x8*)(rowA + kk * 32);
                s16x8 bG = *(const s16x8*)(rowB + kk * 32);
                accA[nt] = __builtin_amdgcn_mfma_f32_16x16x32_bf16(afr[kk], bA, accA[nt], 0, 0, 0);
                accG[nt] = __builtin_amdgcn_mfma_f32_16x16x32_bf16(afr[kk], bG, accG[nt], 0, 0, 0);
            }
        }
        float v0 = 0.f, v1 = 0.f, v2 = 0.f, v3 = 0.f;
        #pragma unroll
        for (int nt = 0; nt < 6; ++nt) {
            int f = nt * 16 + ln15;
            float bav = ba[h * E_ + f];
            float bbv = bb[h * E_ + f];
            float wcv = Wc[h * E_ + f];
            v0 += fast_tanh(accA[nt][0] + bav) * fast_sigmoid(accG[nt][0] + bbv) * wcv;
            v1 += fast_tanh(accA[nt][1] + bav) * fast_sigmoid(accG[nt][1] + bbv) * wcv;
            v2 += fast_tanh(accA[nt][2] + bav) * fast_sigmoid(accG[nt][2] + bbv) * wcv;
            v3 += fast_tanh(accA[nt][3] + bav) * fast_sigmoid(accG[nt][3] + bbv) * wcv;
        }
        hacc[0] += v0; hacc[1] += v1; hacc[2] += v2; hacc[3] += v3;
    }

    #pragma unroll
    for (int r = 0; r < 4; ++r) {
        float v = hacc[r];
        v += __shfl_xor(v, 1, 64);
        v += __shfl_xor(v, 2, 64);
        v += __shfl_xor(v, 4, 64);
        v += __shfl_xor(v, 8, 64);
        hacc[r] = v;
    }
    if (ln15 == 0) {
        #pragma unroll
        for (int r = 0; r < 4; ++r)
            red2[q * 4 + r][wv] = hacc[r];
    }
    __syncthreads();

    if (tid < TT) {
        float bcsum = 0.0f;
        #pragma unroll
        for (int h2 = 0; h2 < H_; ++h2) bcsum += bc[h2];
        s_out[bt0 + tid] = (red2[tid][0] + red2[tid][1] + red2[tid][2] + red2[tid][3]
                            + bcsum) * (1.0f / H_);
    }
}

// ---------------------------------------------------------------------------
// Kernel 2a: per-1024-token chunk max + sum(exp(s - m_c)). grid = B*8.
// ---------------------------------------------------------------------------
__global__ __launch_bounds__(256)
void k2a_chunk(const float* __restrict__ s, float* __restrict__ mzc)
{
    __shared__ float red[8];
    const int blk = blockIdx.x, tid = threadIdx.x, lane = tid & 63, wv = tid >> 6;
    const float* sb = s + (size_t)blk * 1024;

    float v0 = sb[tid], v1 = sb[tid + 256], v2 = sb[tid + 512], v3 = sb[tid + 768];

    float m = fmaxf(fmaxf(v0, v1), fmaxf(v2, v3));
    #pragma unroll
    for (int o = 32; o > 0; o >>= 1) m = fmaxf(m, __shfl_down(m, o, 64));
    if (lane == 0) red[wv] = m;
    __syncthreads();
    m = fmaxf(fmaxf(red[0], red[1]), fmaxf(red[2], red[3]));
    __syncthreads();

    float z = __expf(v0 - m) + __expf(v1 - m) + __expf(v2 - m) + __expf(v3 - m);
    #pragma unroll
    for (int o = 32; o > 0; o >>= 1) z += __shfl_down(z, o, 64);
    if (lane == 0) red[wv] = z;
    __syncthreads();
    if (tid == 0) {
        mzc[blk * 2]     = m;
        mzc[blk * 2 + 1] = red[0] + red[1] + red[2] + red[3];
    }
}

// ---------------------------------------------------------------------------
// Kernel 3: pooling from bf16 xn with 1-ahead prefetch (R11 kA technique).
// Per-block in-register combine of the 8 chunk (m,z) pairs replaces k2b
// (identical expressions -> identical bits). Block LDS-reduces 4 wave
// partials -> one row per block.
// ---------------------------------------------------------------------------
__global__ __launch_bounds__(256)
void k3_pool(const short* __restrict__ xnb, const float* __restrict__ s,
             const float* __restrict__ mzc, float* __restrict__ partial)
{
    __shared__ float red[4][D_];   // 12 KB
    const int tid  = threadIdx.x;
    const int lane = tid & 63;
    const int wv   = tid >> 6;
    const int b    = blockIdx.x / NCH3, ch = blockIdx.x % NCH3;
    const int t0   = b * T_ + ch * CHT3 + wv * 32;

    // combine chunk (m,z) -> batch (m, inv)  [was k2b; same expressions]
    float m = -INFINITY;
    #pragma unroll
    for (int c = 0; c < 8; ++c) m = fmaxf(m, mzc[(b * 8 + c) * 2]);
    float z = 0.0f;
    #pragma unroll
    for (int c = 0; c < 8; ++c)
        z += mzc[(b * 8 + c) * 2 + 1] * __expf(mzc[(b * 8 + c) * 2] - m);
    const float inv = 1.0f / z;

    float acc[12];
    #pragma unroll
    for (int k = 0; k < 12; ++k) acc[k] = 0.0f;

    // 1-ahead prefetch over 32 tokens
    const short* row0 = xnb + (size_t)t0 * D_;
    s16x8 c0 = *(const s16x8*)&row0[8 * lane];
    s16x4 c1 = *(const s16x4*)&row0[512 + 4 * lane];
    float sv = s[t0];

    #pragma unroll 4
    for (int tt = 0; tt < 32; ++tt) {
        s16x8 n0;
        s16x4 n1;
        float ns = 0.0f;
        if (tt < 31) {
            const short* nr = xnb + (size_t)(t0 + tt + 1) * D_;
            n0 = *(const s16x8*)&nr[8 * lane];
            n1 = *(const s16x4*)&nr[512 + 4 * lane];
            ns = s[t0 + tt + 1];
        }

        float wt = __expf(sv - m) * inv;
        #pragma unroll
        for (int k = 0; k < 8; ++k) acc[k] = fmaf(wt, bf2f(c0[k]), acc[k]);
        #pragma unroll
        for (int k = 0; k < 4; ++k) acc[8 + k] = fmaf(wt, bf2f(c1[k]), acc[8 + k]);

        if (tt < 31) { c0 = n0; c1 = n1; sv = ns; }
    }

    *(f32x4*)&red[wv][8 * lane]       = (f32x4){acc[0], acc[1], acc[2], acc[3]};
    *(f32x4*)&red[wv][8 * lane + 4]   = (f32x4){acc[4], acc[5], acc[6], acc[7]};
    *(f32x4*)&red[wv][512 + 4 * lane] = (f32x4){acc[8], acc[9], acc[10], acc[11]};
    __syncthreads();

    float* p = partial + (size_t)blockIdx.x * D_;
    #pragma unroll
    for (int k = 0; k < 3; ++k) {
        int j = tid + k * 256;
        p[j] = ((red[0][j] + red[1][j]) + red[2][j]) + red[3][j];
    }
}

// ---------------------------------------------------------------------------
// Kernel 4: reduce 64 chunk-partials per batch -> out[b, 768].
// grid = B*3 (one block per 256-feature third) for 3x parallelism; same
// ascending-chunk sum order -> identical bits.
// ---------------------------------------------------------------------------
__global__ __launch_bounds__(256)
void k4_reduce(const float* __restrict__ partial, float* __restrict__ out)
{
    const int b = blockIdx.x / 3, third = blockIdx.x % 3, tid = threadIdx.x;
    const int j = third * 256 + tid;
    const float* p = partial + (size_t)b * NCH3 * D_ + j;
    float sum = 0.0f;
    for (int c = 0; c < NCH3; ++c) sum += p[(size_t)c * D_];
    out[b * D_ + j] = sum;
}

// ---------------------------------------------------------------------------
extern "C" void kernel_launch(void* const* d_in, const int* in_sizes, int n_in,
                              void* d_out, int out_size, void* d_ws, size_t ws_size,
                              hipStream_t stream)
{
    const float* x     = (const float*)d_in[0];
    // d_in[1] = lens (unused: uniform == L_IN, reference ignores it)
    const float* gamma = (const float*)d_in[2];
    const float* beta  = (const float*)d_in[3];
    const float* Wa    = (const float*)d_in[4];
    const float* ba    = (const float*)d_in[5];
    const float* Wb    = (const float*)d_in[6];
    const float* bb    = (const float*)d_in[7];
    const float* Wc    = (const float*)d_in[8];
    const float* bc    = (const float*)d_in[9];
    float* out = (float*)d_out;

    float* ws      = (float*)d_ws;
    float* s       = ws;                                   // B*T f32
    float* mzc     = s + B_ * T_;                          // 128 f32
    float* partial = mzc + 128;                            // B*64*768 f32
    short* wtA     = (short*)(partial + (size_t)B_ * NCH3 * D_);
    short* wtB     = wtA + H_ * E_ * E_;
    short* xnb     = wtB + H_ * E_ * E_;                   // B*T*768 bf16 (96 MB)

    hipLaunchKernelGGL(k0_wprep, dim3((H_ * E_ * E_ + 255) / 256), dim3(256), 0, stream,
                       Wa, Wb, wtA, wtB);
    hipLaunchKernelGGL(kA_resln, dim3(NWA / 4), dim3(256), 0, stream,
                       x, gamma, beta, xnb);
    hipLaunchKernelGGL(kB_score, dim3(B_ * T_ / TT), dim3(256), 0, stream,
                       xnb, wtA, wtB, ba, bb, Wc, bc, s);
    hipLaunchKernelGGL(k2a_chunk, dim3(B_ * 8), dim3(256), 0, stream, s, mzc);
    hipLaunchKernelGGL(k3_pool, dim3(B_ * NCH3), dim3(256), 0, stream,
                       xnb, s, mzc, partial);
    hipLaunchKernelGGL(k4_reduce, dim3(B_ * 3), dim3(256), 0, stream, partial, out);
}

// Round 14
// 234.580 us; speedup vs baseline: 1.9344x; 1.0095x over previous
//
#include <hip/hip_runtime.h>
#include <math.h>

// Problem constants (fixed by setup_inputs)
#define B_    8
#define T_    8192
#define LIN   1536
#define D_    768
#define H_    8
#define E_    96
#define TT    16            // tokens per block in kB (24KB LDS -> 6 blocks/CU)
#define NWA   8192          // total waves in kA (2048 blocks x 4 waves); 8 tokens/wave
#define BPB   (T_ / TT)     // 512 kB-blocks per batch

typedef float f32x4 __attribute__((ext_vector_type(4)));
typedef short s16x8 __attribute__((ext_vector_type(8)));
typedef short s16x4 __attribute__((ext_vector_type(4)));

static __device__ __forceinline__ float fast_sigmoid(float v) {
    return 1.0f / (1.0f + __expf(-v));
}
static __device__ __forceinline__ float fast_tanh(float v) {
    float t = __expf(-2.0f * v);
    return (1.0f - t) / (1.0f + t);
}
static __device__ __forceinline__ short f2bf(float f) {   // RNE f32 -> bf16 bits
    unsigned u = __float_as_uint(f);
    unsigned r = (u + 0x7FFFu + ((u >> 16) & 1u)) >> 16;
    return (short)r;
}
static __device__ __forceinline__ float bf2f(short s) {
    return __uint_as_float(((unsigned)(unsigned short)s) << 16);
}

// ---------------------------------------------------------------------------
// Kernel 0: weight prep. Wa,Wb [h][e][f] f32 -> wtA,wtB [h][f][e] bf16.
// ---------------------------------------------------------------------------
__global__ __launch_bounds__(256)
void k0_wprep(const float* __restrict__ Wa, const float* __restrict__ Wb,
              short* __restrict__ wtA, short* __restrict__ wtB)
{
    int o = blockIdx.x * 256 + threadIdx.x;
    if (o >= H_ * E_ * E_) return;
    int e = o % E_;
    int f = (o / E_) % E_;
    int h = o / (E_ * E_);
    int in = h * E_ * E_ + e * E_ + f;
    wtA[o] = f2bf(Wa[in]);
    wtB[o] = f2bf(Wb[in]);
}

// ---------------------------------------------------------------------------
// Kernel A: resize + LayerNorm; wave owns 8 contiguous tokens; 1-ahead
// prefetch. Byte-identical to R11 (passed; measured ~103 us in R12).
// ---------------------------------------------------------------------------
__global__ __launch_bounds__(256)
void kA_resln(const float* __restrict__ x,
              const float* __restrict__ gamma, const float* __restrict__ beta,
              short* __restrict__ xnb)
{
    const int tid  = threadIdx.x;
    const int lane = tid & 63;
    const int wv   = tid >> 6;
    const int gw   = blockIdx.x * 4 + wv;   // 0..NWA-1

    const float SCALE = (float)(1535.0 / 767.0);
    float gm[12], btv[12], wl[12];
    #pragma unroll
    for (int c = 0; c < 3; ++c)
        #pragma unroll
        for (int d = 0; d < 4; ++d) {
            int k = 4 * c + d;
            int j = 256 * c + 4 * lane + d;
            float pos = (float)j * SCALE;
            int a = (int)floorf(pos);
            if (a > LIN - 1) a = LIN - 1;
            wl[k] = pos - (float)a;
            gm[k]  = gamma[j];
            btv[k] = beta[j];
        }
    const bool last = (lane == 63);

    const size_t tok0 = (size_t)gw * 8;
    const float* base = x + tok0 * LIN;

    f32x4 La0 = *(const f32x4*)&base[           8 * lane];
    f32x4 Lb0 = *(const f32x4*)&base[           8 * lane + 4];
    f32x4 La1 = *(const f32x4*)&base[512  +     8 * lane];
    f32x4 Lb1 = *(const f32x4*)&base[512  +     8 * lane + 4];
    f32x4 La2 = *(const f32x4*)&base[1024 +     8 * lane];
    f32x4 Lb2 = *(const f32x4*)&base[1024 +     8 * lane + 4];

    #pragma unroll
    for (int tt = 0; tt < 8; ++tt) {
        f32x4 Na0, Nb0, Na1, Nb1, Na2, Nb2;
        if (tt < 7) {
            const float* nr = base + (size_t)(tt + 1) * LIN;
            Na0 = *(const f32x4*)&nr[           8 * lane];
            Nb0 = *(const f32x4*)&nr[           8 * lane + 4];
            Na1 = *(const f32x4*)&nr[512  +     8 * lane];
            Nb1 = *(const f32x4*)&nr[512  +     8 * lane + 4];
            Na2 = *(const f32x4*)&nr[1024 +     8 * lane];
            Nb2 = *(const f32x4*)&nr[1024 +     8 * lane + 4];
        }

        float xr[12];
        float sum = 0.0f, ssq = 0.0f;
        #pragma unroll
        for (int c = 0; c < 3; ++c) {
            f32x4 A = (c == 0) ? La0 : (c == 1) ? La1 : La2;
            f32x4 Bv = (c == 0) ? Lb0 : (c == 1) ? Lb1 : Lb2;
            #pragma unroll
            for (int d = 0; d < 4; ++d) {
                int k = 4 * c + d;
                int idx = (d & 1) * 2;
                float lo = (d < 2) ? A[idx]     : Bv[idx];
                float hi = (d < 2) ? A[idx + 1] : Bv[idx + 1];
                if (c == 2 && d == 3 && last && wl[k] == 0.0f)
                    lo = Lb2[3];               // j=767 clamp
                float v = lo * (1.0f - wl[k]) + hi * wl[k];
                xr[k] = v; sum += v; ssq = fmaf(v, v, ssq);
            }
        }

        #pragma unroll
        for (int o = 1; o < 64; o <<= 1) {
            sum += __shfl_xor(sum, o, 64);
            ssq += __shfl_xor(ssq, o, 64);
        }
        float mu = sum * (1.0f / D_);
        float rs = 1.0f / sqrtf(ssq * (1.0f / D_) - mu * mu + 1e-5f);

        short* dst = xnb + (tok0 + tt) * D_;
        #pragma unroll
        for (int c = 0; c < 3; ++c) {
            s16x4 p;
            #pragma unroll
            for (int d = 0; d < 4; ++d) {
                int k = 4 * c + d;
                p[d] = f2bf((xr[k] - mu) * rs * gm[k] + btv[k]);
            }
            *(s16x4*)&dst[256 * c + 4 * lane] = p;
        }

        if (tt < 7) {
            La0 = Na0; Lb0 = Nb0; La1 = Na1; Lb1 = Nb1; La2 = Na2; Lb2 = Nb2;
        }
    }
}

// ---------------------------------------------------------------------------
// Kernel B: MFMA scoring + ONLINE-SOFTMAX PARTIAL POOLING (new).
// MFMA core verbatim from R11 (passed). After scoring, the block computes its
// 16 final scores, block max m_b, z_b = sum(exp(s-m_b)), and the unnormalized
// pooled partial P_b[j'] = sum_t exp(s_t - m_b) * xn[t][j'] read straight from
// the LDS tile (head-major index j' = h*96+e). Outputs: partial[4096][768],
// mzb[4096][2]. The s buffer / k2a / k3 are eliminated.
// ---------------------------------------------------------------------------
__global__ __launch_bounds__(256)
void kB_score(const short* __restrict__ xnb,
              const short* __restrict__ wtA, const short* __restrict__ wtB,
              const float* __restrict__ ba, const float* __restrict__ bb,
              const float* __restrict__ Wc, const float* __restrict__ bc,
              float* __restrict__ partial, float* __restrict__ mzb)
{
    __shared__ __align__(16) short xnt[TT * D_];   // 24 KB bf16 tile
    __shared__ float red2[TT][4];
    __shared__ float scs[TT];

    const int tid  = threadIdx.x;
    const int lane = tid & 63;
    const int wv   = tid >> 6;
    const int bt0  = blockIdx.x * TT;

    // ---- Stage 1: global (feature-major) -> LDS (head-major, swizzled) ----
    #pragma unroll
    for (int i = 0; i < 6; ++i) {
        int chunk = i * 256 + tid;
        int tok   = chunk / 96;
        int e     = chunk % 96;
        s16x8 v = *(const s16x8*)&xnb[(size_t)(bt0 + tok) * D_ + e * 8];
        int base = tok * D_;
        int swz  = (tok & 7) << 3;
        #pragma unroll
        for (int h = 0; h < 8; ++h) {
            int sidx = (base + h * E_ + e) ^ swz;
            xnt[sidx] = v[h];
        }
    }
    __syncthreads();

    // ---- Stage 2: MFMA scoring (verbatim R11) ----
    const int ln15 = lane & 15;
    const int q    = lane >> 4;
    const int tokA = ln15;
    const int swzA = (tokA & 7) << 3;

    float hacc[4] = {0.0f, 0.0f, 0.0f, 0.0f};

    #pragma unroll
    for (int hh = 0; hh < 2; ++hh) {
        const int h = wv * 2 + hh;
        s16x8 afr[3];
        #pragma unroll
        for (int kk = 0; kk < 3; ++kk) {
            int sidx = (tokA * D_ + h * E_ + kk * 32 + q * 8) ^ swzA;
            afr[kk] = *(const s16x8*)&xnt[sidx];
        }
        f32x4 accA[6], accG[6];
        #pragma unroll
        for (int nt = 0; nt < 6; ++nt) {
            accA[nt] = (f32x4){0.f, 0.f, 0.f, 0.f};
            accG[nt] = (f32x4){0.f, 0.f, 0.f, 0.f};
        }
        #pragma unroll
        for (int nt = 0; nt < 6; ++nt) {
            const short* rowA = wtA + h * (E_ * E_) + (nt * 16 + ln15) * E_ + q * 8;
            const short* rowB = wtB + h * (E_ * E_) + (nt * 16 + ln15) * E_ + q * 8;
            #pragma unroll
            for (int kk = 0; kk < 3; ++kk) {
                s16x8 bA = *(const s16x8*)(rowA + kk * 32);
                s16x8 bG = *(const s16x8*)(rowB + kk * 32);
                accA[nt] = __builtin_amdgcn_mfma_f32_16x16x32_bf16(afr[kk], bA, accA[nt], 0, 0, 0);
                accG[nt] = __builtin_amdgcn_mfma_f32_16x16x32_bf16(afr[kk], bG, accG[nt], 0, 0, 0);
            }
        }
        float v0 = 0.f, v1 = 0.f, v2 = 0.f, v3 = 0.f;
        #pragma unroll
        for (int nt = 0; nt < 6; ++nt) {
            int f = nt * 16 + ln15;
            float bav = ba[h * E_ + f];
            float bbv = bb[h * E_ + f];
            float wcv = Wc[h * E_ + f];
            v0 += fast_tanh(accA[nt][0] + bav) * fast_sigmoid(accG[nt][0] + bbv) * wcv;
            v1 += fast_tanh(accA[nt][1] + bav) * fast_sigmoid(accG[nt][1] + bbv) * wcv;
            v2 += fast_tanh(accA[nt][2] + bav) * fast_sigmoid(accG[nt][2] + bbv) * wcv;
            v3 += fast_tanh(accA[nt][3] + bav) * fast_sigmoid(accG[nt][3] + bbv) * wcv;
        }
        hacc[0] += v0; hacc[1] += v1; hacc[2] += v2; hacc[3] += v3;
    }

    #pragma unroll
    for (int r = 0; r < 4; ++r) {
        float v = hacc[r];
        v += __shfl_xor(v, 1, 64);
        v += __shfl_xor(v, 2, 64);
        v += __shfl_xor(v, 4, 64);
        v += __shfl_xor(v, 8, 64);
        hacc[r] = v;
    }
    if (ln15 == 0) {
        #pragma unroll
        for (int r = 0; r < 4; ++r)
            red2[q * 4 + r][wv] = hacc[r];
    }
    __syncthreads();

    // ---- Stage 3: final scores for the 16 tokens ----
    if (tid < TT) {
        float bcsum = 0.0f;
        #pragma unroll
        for (int h2 = 0; h2 < H_; ++h2) bcsum += bc[h2];
        scs[tid] = (red2[tid][0] + red2[tid][1] + red2[tid][2] + red2[tid][3]
                    + bcsum) * (1.0f / H_);
    }
    __syncthreads();

    // ---- Stage 4: block-local softmax weights + partial pool from LDS ----
    float sloc[TT];
    #pragma unroll
    for (int t = 0; t < TT; ++t) sloc[t] = scs[t];
    float mb = sloc[0];
    #pragma unroll
    for (int t = 1; t < TT; ++t) mb = fmaxf(mb, sloc[t]);
    float wt[TT];
    float zb = 0.0f;
    #pragma unroll
    for (int t = 0; t < TT; ++t) { wt[t] = __expf(sloc[t] - mb); zb += wt[t]; }
    if (tid == 0) {
        mzb[blockIdx.x * 2]     = mb;
        mzb[blockIdx.x * 2 + 1] = zb;
    }

    float* pp = partial + (size_t)blockIdx.x * D_;
    #pragma unroll
    for (int kk = 0; kk < 3; ++kk) {
        int jp = kk * 256 + tid;   // head-major feature index j' = h*96+e
        float a = 0.0f;
        #pragma unroll
        for (int t = 0; t < TT; ++t)
            a = fmaf(wt[t], bf2f(xnt[(t * D_ + jp) ^ ((t & 7) << 3)]), a);
        pp[jp] = a;
    }
}

// ---------------------------------------------------------------------------
// Kernel MZ: per-batch combine of 512 block (m,z) -> (M, 1/Z). grid = B.
// ---------------------------------------------------------------------------
__global__ __launch_bounds__(256)
void kMZ(const float* __restrict__ mzb, float* __restrict__ MZ)
{
    __shared__ float red[8];
    __shared__ float Msh;
    const int b = blockIdx.x, tid = threadIdx.x, lane = tid & 63, wv = tid >> 6;
    const float* p = mzb + (size_t)b * BPB * 2;

    float m0 = p[tid * 2], m1 = p[(tid + 256) * 2];
    float z0 = p[tid * 2 + 1], z1 = p[(tid + 256) * 2 + 1];

    float M = fmaxf(m0, m1);
    #pragma unroll
    for (int o = 32; o > 0; o >>= 1) M = fmaxf(M, __shfl_down(M, o, 64));
    if (lane == 0) red[wv] = M;
    __syncthreads();
    if (tid == 0) Msh = fmaxf(fmaxf(red[0], red[1]), fmaxf(red[2], red[3]));
    __syncthreads();
    M = Msh;

    float Z = z0 * __expf(m0 - M) + z1 * __expf(m1 - M);
    #pragma unroll
    for (int o = 32; o > 0; o >>= 1) Z += __shfl_down(Z, o, 64);
    if (lane == 0) red[wv] = Z;
    __syncthreads();
    if (tid == 0) {
        float z = red[0] + red[1] + red[2] + red[3];
        MZ[b * 2]     = M;
        MZ[b * 2 + 1] = 1.0f / z;
    }
}

// ---------------------------------------------------------------------------
// Kernel 4: combine 512 partials per batch with scales exp(m_b-M)/Z ->
// out[b, 768]. grid = B*3 (one block per 256-feature third of j'-space).
// Scales precomputed in LDS. Output permuted j' = h*96+e -> j = e*8+h.
// ---------------------------------------------------------------------------
__global__ __launch_bounds__(256)
void k4_reduce(const float* __restrict__ partial, const float* __restrict__ mzb,
               const float* __restrict__ MZ, float* __restrict__ out)
{
    __shared__ float sc[BPB];
    const int b = blockIdx.x / 3, third = blockIdx.x % 3, tid = threadIdx.x;
    const float M = MZ[b * 2], Zinv = MZ[b * 2 + 1];

    const float* pm = mzb + (size_t)b * BPB * 2;
    sc[tid]       = __expf(pm[tid * 2] - M) * Zinv;
    sc[tid + 256] = __expf(pm[(tid + 256) * 2] - M) * Zinv;
    __syncthreads();

    const int jp = third * 256 + tid;
    const float* pp = partial + (size_t)b * BPB * D_ + jp;
    float sum = 0.0f;
    for (int c = 0; c < BPB; ++c)
        sum = fmaf(pp[(size_t)c * D_], sc[c], sum);

    int h = jp / 96, e = jp % 96;
    out[b * D_ + e * 8 + h] = sum;
}

// ---------------------------------------------------------------------------
extern "C" void kernel_launch(void* const* d_in, const int* in_sizes, int n_in,
                              void* d_out, int out_size, void* d_ws, size_t ws_size,
                              hipStream_t stream)
{
    const float* x     = (const float*)d_in[0];
    // d_in[1] = lens (unused: uniform == L_IN, reference ignores it)
    const float* gamma = (const float*)d_in[2];
    const float* beta  = (const float*)d_in[3];
    const float* Wa    = (const float*)d_in[4];
    const float* ba    = (const float*)d_in[5];
    const float* Wb    = (const float*)d_in[6];
    const float* bb    = (const float*)d_in[7];
    const float* Wc    = (const float*)d_in[8];
    const float* bc    = (const float*)d_in[9];
    float* out = (float*)d_out;

    float* ws      = (float*)d_ws;
    float* partial = ws;                                   // B*512*768 f32 (12.6 MB)
    float* mzb     = partial + (size_t)B_ * BPB * D_;      // B*512*2 f32 (32 KB)
    float* MZ      = mzb + (size_t)B_ * BPB * 2;           // 16 f32
    short* wtA     = (short*)(MZ + 16);                    // H*E*E bf16
    short* wtB     = wtA + H_ * E_ * E_;
    short* xnb     = wtB + H_ * E_ * E_;                   // B*T*768 bf16 (96 MB)

    hipLaunchKernelGGL(k0_wprep, dim3((H_ * E_ * E_ + 255) / 256), dim3(256), 0, stream,
                       Wa, Wb, wtA, wtB);
    hipLaunchKernelGGL(kA_resln, dim3(NWA / 4), dim3(256), 0, stream,
                       x, gamma, beta, xnb);
    hipLaunchKernelGGL(kB_score, dim3(B_ * T_ / TT), dim3(256), 0, stream,
                       xnb, wtA, wtB, ba, bb, Wc, bc, partial, mzb);
    hipLaunchKernelGGL(kMZ, dim3(B_), dim3(256), 0, stream, mzb, MZ);
    hipLaunchKernelGGL(k4_reduce, dim3(B_ * 3), dim3(256), 0, stream,
                       partial, mzb, MZ, out);
}